// Round 3
// baseline (1128.260 us; speedup 1.0000x reference)
//
#include <hip/hip_runtime.h>
#include <hip/hip_bf16.h>

typedef __bf16 bf16x8 __attribute__((ext_vector_type(8)));
typedef __bf16 bf16x4 __attribute__((ext_vector_type(4)));
typedef float  f32x4  __attribute__((ext_vector_type(4)));

#define SEQ  4096
#define NH   16
#define HD   128
#define QBLK 128
#define KVBLK 64
#define STR  (NH*HD)   // 2048 floats per seq position

__device__ __forceinline__ bf16x8 cvt_bf16x8(f32x4 a, f32x4 b, float scale) {
    bf16x8 v;
    v[0] = (__bf16)(a[0]*scale); v[1] = (__bf16)(a[1]*scale);
    v[2] = (__bf16)(a[2]*scale); v[3] = (__bf16)(a[3]*scale);
    v[4] = (__bf16)(b[0]*scale); v[5] = (__bf16)(b[1]*scale);
    v[6] = (__bf16)(b[2]*scale); v[7] = (__bf16)(b[3]*scale);
    return v;
}

// V^T swizzle: bits 3-5 of element index, function of d only; keeps
// b128 reads (8 consec kv) and b64 writes (4 consec kv) contiguous.
__device__ __forceinline__ int vswz(int d) { return ((d & 7) ^ ((d >> 3) & 7)) << 3; }

__global__ __launch_bounds__(256, 3) void fattn_kernel(
    const float* __restrict__ Q, const float* __restrict__ K,
    const float* __restrict__ V, float* __restrict__ O)
{
    __shared__ __align__(16) __bf16 ldsK[KVBLK * HD];    // 16 KB
    __shared__ __align__(16) __bf16 ldsVT[HD * KVBLK];   // 16 KB
    __shared__ __align__(16) __bf16 ldsPT[4][KVBLK * 20]; // 10 KB

    const int tid  = threadIdx.x;
    const int lane = tid & 63;
    const int wv   = tid >> 6;
    const int c    = lane & 15;
    const int g    = lane >> 4;

    const int h  = blockIdx.x & (NH - 1);
    const int qb = (SEQ / QBLK) - 1 - (int)(blockIdx.x >> 4); // heavy first
    const int q0 = qb * QBLK;

    const float scale = 0.08838834764831845f;  // 1/sqrt(128)

    // ---- Q fragments: 32 rows per wave (2 subtiles of 16) ----
    bf16x8 qf[2][4];
    #pragma unroll
    for (int sub = 0; sub < 2; ++sub) {
        const float* qrow = Q + (size_t)(q0 + wv*32 + sub*16 + c) * STR + h*HD;
        #pragma unroll
        for (int ks = 0; ks < 4; ++ks) {
            const int d0 = 32*ks + 8*g;
            f32x4 a = *(const f32x4*)(qrow + d0);
            f32x4 b = *(const f32x4*)(qrow + d0 + 4);
            qf[sub][ks] = cvt_bf16x8(a, b, scale);
        }
    }

    f32x4 oacc[2][8];
    #pragma unroll
    for (int s2 = 0; s2 < 2; ++s2)
        #pragma unroll
        for (int i = 0; i < 8; ++i) { oacc[s2][i][0]=0.f; oacc[s2][i][1]=0.f; oacc[s2][i][2]=0.f; oacc[s2][i][3]=0.f; }
    float mrow[2][4] = {{-1e30f,-1e30f,-1e30f,-1e30f},{-1e30f,-1e30f,-1e30f,-1e30f}};
    float lrow[2][4] = {{0.f,0.f,0.f,0.f},{0.f,0.f,0.f,0.f}};

    // ---- staging registers (tile double-buffer lives in regs) ----
    bf16x8 kst[4];   // K: 4 x (row, 8-elem chunk)
    bf16x4 vst[8];   // V^T: 8 x (d, 4 consecutive kv)
    const int krb  = tid >> 4;        // K row base within 16-row group
    const int kch  = tid & 15;        // K 8-float chunk
    const int vkv0 = 4 * (tid >> 4);  // V: 4 kv rows starting here
    const int vd0  = 4 * (tid & 15);  // V: 4 d cols starting here

    #define LOAD_TILE(K0)                                                        \
    {                                                                            \
        _Pragma("unroll")                                                        \
        for (int it = 0; it < 4; ++it) {                                         \
            const int row = it*16 + krb;                                         \
            const float* src = K + (size_t)((K0)+row)*STR + h*HD + kch*8;        \
            f32x4 a = *(const f32x4*)src;                                        \
            f32x4 b = *(const f32x4*)(src + 4);                                  \
            kst[it] = cvt_bf16x8(a, b, 1.0f);                                    \
        }                                                                        \
        _Pragma("unroll")                                                        \
        for (int ith = 0; ith < 2; ++ith) {                                      \
            const int d = vd0 + 64*ith;                                          \
            f32x4 va0 = *(const f32x4*)(V + (size_t)((K0)+vkv0+0)*STR + h*HD + d);\
            f32x4 va1 = *(const f32x4*)(V + (size_t)((K0)+vkv0+1)*STR + h*HD + d);\
            f32x4 va2 = *(const f32x4*)(V + (size_t)((K0)+vkv0+2)*STR + h*HD + d);\
            f32x4 va3 = *(const f32x4*)(V + (size_t)((K0)+vkv0+3)*STR + h*HD + d);\
            _Pragma("unroll")                                                    \
            for (int i = 0; i < 4; ++i) {                                        \
                bf16x4 t;                                                        \
                t[0] = (__bf16)va0[i]; t[1] = (__bf16)va1[i];                    \
                t[2] = (__bf16)va2[i]; t[3] = (__bf16)va3[i];                    \
                vst[ith*4 + i] = t;                                              \
            }                                                                    \
        }                                                                        \
    }

    const int nkv = 2*qb + 2;
    LOAD_TILE(0);

    for (int kb = 0; kb < nkv; ++kb) {
        const int k0 = kb * KVBLK;

        __syncthreads();   // previous iteration's LDS reads complete
        // ---- reg -> LDS: K tile (b128, swizzled) ----
        #pragma unroll
        for (int it = 0; it < 4; ++it) {
            const int row = it*16 + krb;
            const int e = (row*HD + kch*8) ^ ((row & 7) << 3);
            *(bf16x8*)&ldsK[e] = kst[it];
        }
        // ---- reg -> LDS: V^T tile (b64, swizzled) ----
        #pragma unroll
        for (int ith = 0; ith < 2; ++ith)
            #pragma unroll
            for (int i = 0; i < 4; ++i) {
                const int d = vd0 + 64*ith + i;
                const int e = (d*KVBLK + vkv0) ^ vswz(d);
                *(bf16x4*)&ldsVT[e] = vst[ith*4 + i];
            }
        __syncthreads();

        // ---- issue next tile's global loads (latency hides under compute) ----
        if (kb + 1 < nkv) LOAD_TILE(k0 + KVBLK);

        #pragma unroll
        for (int sub = 0; sub < 2; ++sub) {
            const int qlo = q0 + wv*32 + sub*16;
            if (k0 > qlo) continue;   // this subtile attends nothing in this kv tile

            // ---- QK^T: S[16 q][64 k] ----
            f32x4 s[4];
            __builtin_amdgcn_s_setprio(1);
            #pragma unroll
            for (int t = 0; t < 4; ++t) {
                f32x4 acc = {0.f,0.f,0.f,0.f};
                #pragma unroll
                for (int ks = 0; ks < 4; ++ks) {
                    const int row = t*16 + c;
                    const int e = (row*HD + 32*ks + 8*g) ^ ((row & 7) << 3);
                    bf16x8 bk = *(const bf16x8*)&ldsK[e];
                    acc = __builtin_amdgcn_mfma_f32_16x16x32_bf16(qf[sub][ks], bk, acc, 0, 0, 0);
                }
                s[t] = acc;
            }
            __builtin_amdgcn_s_setprio(0);

            // ---- causal mask (diagonal band only) ----
            if (k0 + KVBLK - 1 > qlo) {
                #pragma unroll
                for (int t = 0; t < 4; ++t)
                    #pragma unroll
                    for (int r = 0; r < 4; ++r) {
                        const int qg = qlo + 4*g + r;
                        const int kg = k0 + t*16 + c;
                        if (kg > qg) s[t][r] = -1e30f;
                    }
            }

            // ---- online softmax (16-lane group reduce) ----
            float alpha[4];
            #pragma unroll
            for (int r = 0; r < 4; ++r) {
                float m0 = fmaxf(fmaxf(s[0][r], s[1][r]), fmaxf(s[2][r], s[3][r]));
                #pragma unroll
                for (int off = 1; off < 16; off <<= 1)
                    m0 = fmaxf(m0, __shfl_xor(m0, off, 64));
                const float mn = fmaxf(mrow[sub][r], m0);
                alpha[r] = __expf(mrow[sub][r] - mn);
                mrow[sub][r] = mn;
            }
            float rs[4] = {0.f,0.f,0.f,0.f};
            #pragma unroll
            for (int t = 0; t < 4; ++t)
                #pragma unroll
                for (int r = 0; r < 4; ++r) {
                    const float p = __expf(s[t][r] - mrow[sub][r]);
                    s[t][r] = p;
                    rs[r] += p;
                }
            #pragma unroll
            for (int r = 0; r < 4; ++r) {
                float x = rs[r];
                #pragma unroll
                for (int off = 1; off < 16; off <<= 1)
                    x += __shfl_xor(x, off, 64);
                lrow[sub][r] = lrow[sub][r]*alpha[r] + x;
            }
            #pragma unroll
            for (int dt = 0; dt < 8; ++dt)
                #pragma unroll
                for (int r = 0; r < 4; ++r)
                    oacc[sub][dt][r] *= alpha[r];

            // ---- P^T via per-wave LDS (b64 packed writes) ----
            #pragma unroll
            for (int t = 0; t < 4; ++t) {
                bf16x4 pv;
                pv[0] = (__bf16)s[t][0]; pv[1] = (__bf16)s[t][1];
                pv[2] = (__bf16)s[t][2]; pv[3] = (__bf16)s[t][3];
                *(bf16x4*)&ldsPT[wv][(t*16 + c)*20 + 4*g] = pv;
            }
            bf16x8 pa[2];
            #pragma unroll
            for (int ks = 0; ks < 2; ++ks) {
                bf16x8 v;
                #pragma unroll
                for (int j = 0; j < 8; ++j)
                    v[j] = ldsPT[wv][(32*ks + 8*g + j)*20 + c];
                pa[ks] = v;
            }

            // ---- PV ----
            __builtin_amdgcn_s_setprio(1);
            #pragma unroll
            for (int dt = 0; dt < 8; ++dt) {
                #pragma unroll
                for (int ks = 0; ks < 2; ++ks) {
                    const int dd = dt*16 + c;
                    const int e = (dd*KVBLK + 32*ks + 8*g) ^ vswz(dd);
                    bf16x8 bv = *(const bf16x8*)&ldsVT[e];
                    oacc[sub][dt] = __builtin_amdgcn_mfma_f32_16x16x32_bf16(pa[ks], bv, oacc[sub][dt], 0, 0, 0);
                }
            }
            __builtin_amdgcn_s_setprio(0);
        }
    }

    // ---- epilogue ----
    #pragma unroll
    for (int sub = 0; sub < 2; ++sub)
        #pragma unroll
        for (int r = 0; r < 4; ++r) {
            const float inv = 1.0f / lrow[sub][r];
            const int qg = q0 + wv*32 + sub*16 + 4*g + r;
            float* orow = O + (size_t)qg*STR + h*HD;
            #pragma unroll
            for (int dt = 0; dt < 8; ++dt)
                orow[dt*16 + c] = oacc[sub][dt][r] * inv;
        }
    #undef LOAD_TILE
}

extern "C" void kernel_launch(void* const* d_in, const int* in_sizes, int n_in,
                              void* d_out, int out_size, void* d_ws, size_t ws_size,
                              hipStream_t stream) {
    const float* Q = (const float*)d_in[0];
    const float* K = (const float*)d_in[1];
    const float* V = (const float*)d_in[2];
    float* O = (float*)d_out;
    dim3 grid((SEQ / QBLK) * NH);   // 32 q-blocks x 16 heads = 512 blocks
    dim3 block(256);
    fattn_kernel<<<grid, block, 0, stream>>>(Q, K, V, O);
}

// Round 5
// 298.575 us; speedup vs baseline: 3.7788x; 3.7788x over previous
//
#include <hip/hip_runtime.h>
#include <hip/hip_bf16.h>

typedef __bf16 bf16x8 __attribute__((ext_vector_type(8)));
typedef __bf16 bf16x4 __attribute__((ext_vector_type(4)));
typedef float  f32x4  __attribute__((ext_vector_type(4)));

#define SEQ  4096
#define NH   16
#define HD   128
#define QBLK 128
#define KVBLK 64
#define STR  (NH*HD)   // 2048 floats per seq position

__device__ __forceinline__ bf16x8 cvt_bf16x8(f32x4 a, f32x4 b, float scale) {
    bf16x8 v;
    v[0] = (__bf16)(a[0]*scale); v[1] = (__bf16)(a[1]*scale);
    v[2] = (__bf16)(a[2]*scale); v[3] = (__bf16)(a[3]*scale);
    v[4] = (__bf16)(b[0]*scale); v[5] = (__bf16)(b[1]*scale);
    v[6] = (__bf16)(b[2]*scale); v[7] = (__bf16)(b[3]*scale);
    return v;
}

// V^T swizzle: function of d only; keeps b128 reads (8 consec kv) and
// b64 writes (4 consec kv) contiguous while spreading banks across d.
__device__ __forceinline__ int vswz(int d) { return ((d & 7) ^ ((d >> 3) & 7)) << 3; }

// NOTE: no min-waves arg — R3's __launch_bounds__(256,3) capped VGPR at 84
// and spilled ~500MB/dispatch to scratch (FETCH 73->410MB). Let RA breathe.
__global__ __launch_bounds__(256) void fattn_kernel(
    const float* __restrict__ Q, const float* __restrict__ K,
    const float* __restrict__ V, float* __restrict__ O)
{
    __shared__ __align__(16) __bf16 ldsK[KVBLK * HD];     // 16 KB
    __shared__ __align__(16) __bf16 ldsVT[HD * KVBLK];    // 16 KB
    __shared__ __align__(16) __bf16 ldsPT[4][KVBLK * 20]; // 10 KB

    const int tid  = threadIdx.x;
    const int lane = tid & 63;
    const int wv   = tid >> 6;
    const int c    = lane & 15;
    const int g    = lane >> 4;

    const int h  = blockIdx.x & (NH - 1);
    const int qb = (SEQ / QBLK) - 1 - (int)(blockIdx.x >> 4); // heavy first
    const int q0 = qb * QBLK;

    const float scale = 0.08838834764831845f;  // 1/sqrt(128)

    // ---- Q fragments: 32 rows per wave (2 subtiles of 16) ----
    bf16x8 qf[2][4];
    #pragma unroll
    for (int sub = 0; sub < 2; ++sub) {
        const float* qrow = Q + (size_t)(q0 + wv*32 + sub*16 + c) * STR + h*HD;
        #pragma unroll
        for (int ks = 0; ks < 4; ++ks) {
            const int d0 = 32*ks + 8*g;
            f32x4 a = *(const f32x4*)(qrow + d0);
            f32x4 b = *(const f32x4*)(qrow + d0 + 4);
            qf[sub][ks] = cvt_bf16x8(a, b, scale);
        }
    }

    f32x4 oacc[2][8];
    #pragma unroll
    for (int s2 = 0; s2 < 2; ++s2)
        #pragma unroll
        for (int i = 0; i < 8; ++i) { oacc[s2][i][0]=0.f; oacc[s2][i][1]=0.f; oacc[s2][i][2]=0.f; oacc[s2][i][3]=0.f; }
    float mrow[2][4] = {{-1e30f,-1e30f,-1e30f,-1e30f},{-1e30f,-1e30f,-1e30f,-1e30f}};
    float lrow[2][4] = {{0.f,0.f,0.f,0.f},{0.f,0.f,0.f,0.f}};

    // ---- staging registers (next tile lives in regs while LDS is in use) ----
    bf16x8 kst[4];   // K: 4 x (row, 8-elem chunk)
    bf16x4 vst[8];   // V^T: 8 x (d, 4 consecutive kv)
    const int krb  = tid >> 4;        // K row base within 16-row group
    const int kch  = tid & 15;        // K 8-float chunk
    const int vkv0 = 4 * (tid >> 4);  // V: 4 kv rows starting here
    const int vd0  = 4 * (tid & 15);  // V: 4 d cols starting here

    #define LOAD_TILE(K0)                                                        \
    {                                                                            \
        _Pragma("unroll")                                                        \
        for (int it = 0; it < 4; ++it) {                                         \
            const int row = it*16 + krb;                                         \
            const float* src = K + (size_t)((K0)+row)*STR + h*HD + kch*8;        \
            f32x4 a = *(const f32x4*)src;                                        \
            f32x4 b = *(const f32x4*)(src + 4);                                  \
            kst[it] = cvt_bf16x8(a, b, 1.0f);                                    \
        }                                                                        \
        _Pragma("unroll")                                                        \
        for (int ith = 0; ith < 2; ++ith) {                                      \
            const int d = vd0 + 64*ith;                                          \
            f32x4 va0 = *(const f32x4*)(V + (size_t)((K0)+vkv0+0)*STR + h*HD + d);\
            f32x4 va1 = *(const f32x4*)(V + (size_t)((K0)+vkv0+1)*STR + h*HD + d);\
            f32x4 va2 = *(const f32x4*)(V + (size_t)((K0)+vkv0+2)*STR + h*HD + d);\
            f32x4 va3 = *(const f32x4*)(V + (size_t)((K0)+vkv0+3)*STR + h*HD + d);\
            _Pragma("unroll")                                                    \
            for (int i = 0; i < 4; ++i) {                                        \
                bf16x4 t;                                                        \
                t[0] = (__bf16)va0[i]; t[1] = (__bf16)va1[i];                    \
                t[2] = (__bf16)va2[i]; t[3] = (__bf16)va3[i];                    \
                vst[ith*4 + i] = t;                                              \
            }                                                                    \
        }                                                                        \
    }

    const int nkv = 2*qb + 2;   // kv tiles needed to cover q0+QBLK keys
    LOAD_TILE(0);

    for (int kb = 0; kb < nkv; ++kb) {
        const int k0 = kb * KVBLK;

        __syncthreads();   // previous iteration's LDS reads complete
        // ---- reg -> LDS: K tile (b128, swizzled) ----
        #pragma unroll
        for (int it = 0; it < 4; ++it) {
            const int row = it*16 + krb;
            const int e = (row*HD + kch*8) ^ ((row & 7) << 3);
            *(bf16x8*)&ldsK[e] = kst[it];
        }
        // ---- reg -> LDS: V^T tile (b64, swizzled) ----
        #pragma unroll
        for (int ith = 0; ith < 2; ++ith)
            #pragma unroll
            for (int i = 0; i < 4; ++i) {
                const int d = vd0 + 64*ith + i;
                const int e = (d*KVBLK + vkv0) ^ vswz(d);
                *(bf16x4*)&ldsVT[e] = vst[ith*4 + i];
            }
        __syncthreads();

        // ---- issue next tile's global loads (latency hides under compute) ----
        if (kb + 1 < nkv) LOAD_TILE(k0 + KVBLK);

        #pragma unroll
        for (int sub = 0; sub < 2; ++sub) {
            const int qlo = q0 + wv*32 + sub*16;
            if (k0 > qlo) continue;   // subtile attends nothing in this kv tile

            // ---- QK^T: S[16 q][64 k] ----
            f32x4 s[4];
            __builtin_amdgcn_s_setprio(1);
            #pragma unroll
            for (int t = 0; t < 4; ++t) {
                f32x4 acc = {0.f,0.f,0.f,0.f};
                #pragma unroll
                for (int ks = 0; ks < 4; ++ks) {
                    const int row = t*16 + c;
                    const int e = (row*HD + 32*ks + 8*g) ^ ((row & 7) << 3);
                    bf16x8 bk = *(const bf16x8*)&ldsK[e];
                    acc = __builtin_amdgcn_mfma_f32_16x16x32_bf16(qf[sub][ks], bk, acc, 0, 0, 0);
                }
                s[t] = acc;
            }
            __builtin_amdgcn_s_setprio(0);

            // ---- causal mask (diagonal band only) ----
            if (k0 + KVBLK - 1 > qlo) {
                #pragma unroll
                for (int t = 0; t < 4; ++t)
                    #pragma unroll
                    for (int r = 0; r < 4; ++r) {
                        const int qg = qlo + 4*g + r;
                        const int kg = k0 + t*16 + c;
                        if (kg > qg) s[t][r] = -1e30f;
                    }
            }

            // ---- online softmax (16-lane group reduce) ----
            float alpha[4];
            #pragma unroll
            for (int r = 0; r < 4; ++r) {
                float m0 = fmaxf(fmaxf(s[0][r], s[1][r]), fmaxf(s[2][r], s[3][r]));
                #pragma unroll
                for (int off = 1; off < 16; off <<= 1)
                    m0 = fmaxf(m0, __shfl_xor(m0, off, 64));
                const float mn = fmaxf(mrow[sub][r], m0);
                alpha[r] = __expf(mrow[sub][r] - mn);
                mrow[sub][r] = mn;
            }
            float rs[4] = {0.f,0.f,0.f,0.f};
            #pragma unroll
            for (int t = 0; t < 4; ++t)
                #pragma unroll
                for (int r = 0; r < 4; ++r) {
                    const float p = __expf(s[t][r] - mrow[sub][r]);
                    s[t][r] = p;
                    rs[r] += p;
                }
            #pragma unroll
            for (int r = 0; r < 4; ++r) {
                float x = rs[r];
                #pragma unroll
                for (int off = 1; off < 16; off <<= 1)
                    x += __shfl_xor(x, off, 64);
                lrow[sub][r] = lrow[sub][r]*alpha[r] + x;
            }
            #pragma unroll
            for (int dt = 0; dt < 8; ++dt)
                #pragma unroll
                for (int r = 0; r < 4; ++r)
                    oacc[sub][dt][r] *= alpha[r];

            // ---- P^T via per-wave LDS (b64 packed writes) ----
            #pragma unroll
            for (int t = 0; t < 4; ++t) {
                bf16x4 pv;
                pv[0] = (__bf16)s[t][0]; pv[1] = (__bf16)s[t][1];
                pv[2] = (__bf16)s[t][2]; pv[3] = (__bf16)s[t][3];
                *(bf16x4*)&ldsPT[wv][(t*16 + c)*20 + 4*g] = pv;
            }
            bf16x8 pa[2];
            #pragma unroll
            for (int ks = 0; ks < 2; ++ks) {
                bf16x8 v;
                #pragma unroll
                for (int j = 0; j < 8; ++j)
                    v[j] = ldsPT[wv][(32*ks + 8*g + j)*20 + c];
                pa[ks] = v;
            }

            // ---- PV ----
            __builtin_amdgcn_s_setprio(1);
            #pragma unroll
            for (int dt = 0; dt < 8; ++dt) {
                #pragma unroll
                for (int ks = 0; ks < 2; ++ks) {
                    const int dd = dt*16 + c;
                    const int e = (dd*KVBLK + 32*ks + 8*g) ^ vswz(dd);
                    bf16x8 bv = *(const bf16x8*)&ldsVT[e];
                    oacc[sub][dt] = __builtin_amdgcn_mfma_f32_16x16x32_bf16(pa[ks], bv, oacc[sub][dt], 0, 0, 0);
                }
            }
            __builtin_amdgcn_s_setprio(0);
        }
    }

    // ---- epilogue ----
    #pragma unroll
    for (int sub = 0; sub < 2; ++sub)
        #pragma unroll
        for (int r = 0; r < 4; ++r) {
            const float inv = 1.0f / lrow[sub][r];
            const int qg = q0 + wv*32 + sub*16 + 4*g + r;
            float* orow = O + (size_t)qg*STR + h*HD;
            #pragma unroll
            for (int dt = 0; dt < 8; ++dt)
                orow[dt*16 + c] = oacc[sub][dt][r] * inv;
        }
    #undef LOAD_TILE
}

extern "C" void kernel_launch(void* const* d_in, const int* in_sizes, int n_in,
                              void* d_out, int out_size, void* d_ws, size_t ws_size,
                              hipStream_t stream) {
    const float* Q = (const float*)d_in[0];
    const float* K = (const float*)d_in[1];
    const float* V = (const float*)d_in[2];
    float* O = (float*)d_out;
    dim3 grid((SEQ / QBLK) * NH);   // 32 q-blocks x 16 heads = 512 blocks
    dim3 block(256);
    fattn_kernel<<<grid, block, 0, stream>>>(Q, K, V, O);
}

// Round 7
// 170.881 us; speedup vs baseline: 6.6026x; 1.7473x over previous
//
#include <hip/hip_runtime.h>
#include <hip/hip_bf16.h>

typedef __bf16 bf16x8 __attribute__((ext_vector_type(8)));
typedef __bf16 bf16x4 __attribute__((ext_vector_type(4)));
typedef float  f32x4  __attribute__((ext_vector_type(4)));

#define SEQ  4096
#define NH   16
#define HD   128
#define QBLK 64
#define KVBLK 64
#define STR  (NH*HD)   // 2048 floats per seq position

__device__ __forceinline__ bf16x8 cvt_bf16x8(f32x4 a, f32x4 b, float scale) {
    bf16x8 v;
    v[0] = (__bf16)(a[0]*scale); v[1] = (__bf16)(a[1]*scale);
    v[2] = (__bf16)(a[2]*scale); v[3] = (__bf16)(a[3]*scale);
    v[4] = (__bf16)(b[0]*scale); v[5] = (__bf16)(b[1]*scale);
    v[6] = (__bf16)(b[2]*scale); v[7] = (__bf16)(b[3]*scale);
    return v;
}

// V^T quad-swizzle: function of d only; keeps b128 reads / b64 writes contiguous.
__device__ __forceinline__ int vswz(int d) { return ((d & 7) ^ ((d >> 3) & 7)) << 3; }

// NOTE: no min-waves arg (R3 lesson: capping VGPR spilled 500MB to scratch).
__global__ __launch_bounds__(256) void fattn_kernel(
    const float* __restrict__ Q, const float* __restrict__ K,
    const float* __restrict__ V, float* __restrict__ O)
{
    __shared__ __align__(16) __bf16 ldsK[KVBLK * HD];   // [key][d], 16 KB
    __shared__ __align__(16) __bf16 ldsVT[HD * KVBLK];  // [d][p] sigma-permuted, 16 KB

    const int tid  = threadIdx.x;
    const int lane = tid & 63;
    const int wv   = tid >> 6;
    const int c    = lane & 15;   // q index within 16 (swapped layout)
    const int g    = lane >> 4;   // 16-lane group 0..3

    const int h  = blockIdx.x & (NH - 1);
    const int qb = (SEQ / QBLK) - 1 - (int)(blockIdx.x >> 4); // heavy first
    const int q0 = qb * QBLK;
    const int qg = q0 + wv*16 + c;   // this lane's q row (for S^T columns)

    const float scale = 0.08838834764831845f;  // 1/sqrt(128)

    // ---- Q fragment (B operand): lane holds Q[qg][32ks+8g .. +7] ----
    bf16x8 qf[4];
    {
        const float* qrow = Q + (size_t)qg * STR + h*HD;
        #pragma unroll
        for (int ks = 0; ks < 4; ++ks) {
            const int d0 = 32*ks + 8*g;
            f32x4 a = *(const f32x4*)(qrow + d0);
            f32x4 b = *(const f32x4*)(qrow + d0 + 4);
            qf[ks] = cvt_bf16x8(a, b, scale);
        }
    }

    // O accumulator: lane holds O[q=qlo+4g+r][d=16dt+c]
    f32x4 oacc[8];
    #pragma unroll
    for (int i = 0; i < 8; ++i) { oacc[i][0]=0.f; oacc[i][1]=0.f; oacc[i][2]=0.f; oacc[i][3]=0.f; }
    float mrow = -1e30f;   // running max for q=qg (lane-local!)
    float lrow = 0.f;      // running denom for q=qg

    // ---- staging registers ----
    bf16x8 kst[4];
    bf16x4 vst[8];
    const int krb  = tid >> 4;        // K row base within 16-row group
    const int kch  = tid & 15;        // K 8-float chunk
    const int m_   = tid >> 4;        // V: which 4-key group
    const int vkv0 = 4 * m_;          // V source rows kv0..kv0+3
    const int p0   = 32*(m_>>3) + 8*(m_&3) + 4*((m_>>2)&1);  // sigma(kv0)
    const int vd0  = 4 * (tid & 15);  // V: 4 d cols

    #define LOAD_TILE(K0)                                                        \
    {                                                                            \
        _Pragma("unroll")                                                        \
        for (int it = 0; it < 4; ++it) {                                         \
            const int row = it*16 + krb;                                         \
            const float* src = K + (size_t)((K0)+row)*STR + h*HD + kch*8;        \
            f32x4 a = *(const f32x4*)src;                                        \
            f32x4 b = *(const f32x4*)(src + 4);                                  \
            kst[it] = cvt_bf16x8(a, b, 1.0f);                                    \
        }                                                                        \
        _Pragma("unroll")                                                        \
        for (int ith = 0; ith < 2; ++ith) {                                      \
            const int d = vd0 + 64*ith;                                          \
            f32x4 va0 = *(const f32x4*)(V + (size_t)((K0)+vkv0+0)*STR + h*HD + d);\
            f32x4 va1 = *(const f32x4*)(V + (size_t)((K0)+vkv0+1)*STR + h*HD + d);\
            f32x4 va2 = *(const f32x4*)(V + (size_t)((K0)+vkv0+2)*STR + h*HD + d);\
            f32x4 va3 = *(const f32x4*)(V + (size_t)((K0)+vkv0+3)*STR + h*HD + d);\
            _Pragma("unroll")                                                    \
            for (int i = 0; i < 4; ++i) {                                        \
                bf16x4 t;                                                        \
                t[0] = (__bf16)va0[i]; t[1] = (__bf16)va1[i];                    \
                t[2] = (__bf16)va2[i]; t[3] = (__bf16)va3[i];                    \
                vst[ith*4 + i] = t;                                              \
            }                                                                    \
        }                                                                        \
    }

    const int nkv = qb + 1;   // kv tiles covering keys <= q0+63
    LOAD_TILE(0);

    const int qlo = q0 + wv*16;

    for (int kb = 0; kb < nkv; ++kb) {
        const int k0 = kb * KVBLK;

        __syncthreads();   // previous iteration's LDS reads complete
        // ---- reg -> LDS: K tile [key][d], b128 swizzled ----
        #pragma unroll
        for (int it = 0; it < 4; ++it) {
            const int row = it*16 + krb;
            const int e = (row*HD + kch*8) ^ ((row & 7) << 3);
            *(bf16x8*)&ldsK[e] = kst[it];
        }
        // ---- reg -> LDS: V^T tile [d][p], b64 at sigma(kv0), swizzled ----
        #pragma unroll
        for (int ith = 0; ith < 2; ++ith)
            #pragma unroll
            for (int i = 0; i < 4; ++i) {
                const int d = vd0 + 64*ith + i;
                const int e = (d*KVBLK + p0) ^ vswz(d);
                *(bf16x4*)&ldsVT[e] = vst[ith*4 + i];
            }
        __syncthreads();

        // ---- issue next tile's global loads (hide latency under compute) ----
        if (kb + 1 < nkv) LOAD_TILE(k0 + KVBLK);

        if (k0 <= qlo + 15) {   // else: fully masked for this wave's q rows
            // ---- swapped QK^T: S^T[key][q]; lane gets S^T[k0+16t+4g+r][qg] ----
            f32x4 s[4];
            __builtin_amdgcn_s_setprio(1);
            #pragma unroll
            for (int t = 0; t < 4; ++t) {
                f32x4 acc = {0.f,0.f,0.f,0.f};
                #pragma unroll
                for (int ks = 0; ks < 4; ++ks) {
                    const int row = t*16 + c;   // key within tile
                    const int e = (row*HD + 32*ks + 8*g) ^ ((row & 7) << 3);
                    bf16x8 ak = *(const bf16x8*)&ldsK[e];
                    acc = __builtin_amdgcn_mfma_f32_16x16x32_bf16(ak, qf[ks], acc, 0, 0, 0);
                }
                s[t] = acc;
            }
            __builtin_amdgcn_s_setprio(0);

            // ---- causal mask: only the diagonal tile ----
            if (kb == qb) {
                #pragma unroll
                for (int t = 0; t < 4; ++t)
                    #pragma unroll
                    for (int r = 0; r < 4; ++r)
                        if (k0 + 16*t + 4*g + r > qg) s[t][r] = -1e30f;
            }

            // ---- online softmax for q=qg (lane-local row; reduce over g) ----
            float pmax = fmaxf(
                fmaxf(fmaxf(fmaxf(s[0][0],s[0][1]),fmaxf(s[0][2],s[0][3])),
                      fmaxf(fmaxf(s[1][0],s[1][1]),fmaxf(s[1][2],s[1][3]))),
                fmaxf(fmaxf(fmaxf(s[2][0],s[2][1]),fmaxf(s[2][2],s[2][3])),
                      fmaxf(fmaxf(s[3][0],s[3][1]),fmaxf(s[3][2],s[3][3]))));
            pmax = fmaxf(pmax, __shfl_xor(pmax, 16, 64));
            pmax = fmaxf(pmax, __shfl_xor(pmax, 32, 64));
            const float mn = fmaxf(mrow, pmax);
            const float alpha = __expf(mrow - mn);
            mrow = mn;
            float rs = 0.f;
            #pragma unroll
            for (int t = 0; t < 4; ++t)
                #pragma unroll
                for (int r = 0; r < 4; ++r) {
                    const float p = __expf(s[t][r] - mn);
                    s[t][r] = p;
                    rs += p;
                }
            rs += __shfl_xor(rs, 16, 64);
            rs += __shfl_xor(rs, 32, 64);
            lrow = lrow*alpha + rs;

            // ---- fetch alpha for the oacc rows (q=qlo+4g+r lives at lane c'=4g+r) ----
            f32x4 aq;
            #pragma unroll
            for (int r = 0; r < 4; ++r)
                aq[r] = __shfl(alpha, 20*g + r, 64);   // lane 16g + (4g+r)
            #pragma unroll
            for (int dt = 0; dt < 8; ++dt)
                oacc[dt] *= aq;

            // ---- P -> A-fragment: pure register repack (no LDS!) ----
            // pa[ks] element j = P^T[key=16(2ks+(j>>2))+4g+(j&3)][qg]
            bf16x8 pa[2];
            #pragma unroll
            for (int ks = 0; ks < 2; ++ks) {
                bf16x8 v;
                v[0]=(__bf16)s[2*ks][0];   v[1]=(__bf16)s[2*ks][1];
                v[2]=(__bf16)s[2*ks][2];   v[3]=(__bf16)s[2*ks][3];
                v[4]=(__bf16)s[2*ks+1][0]; v[5]=(__bf16)s[2*ks+1][1];
                v[6]=(__bf16)s[2*ks+1][2]; v[7]=(__bf16)s[2*ks+1][3];
                pa[ks] = v;
            }

            // ---- PV: A=P (row=q), B=V (col=d, sigma-permuted k) ----
            __builtin_amdgcn_s_setprio(1);
            #pragma unroll
            for (int dt = 0; dt < 8; ++dt) {
                #pragma unroll
                for (int ks = 0; ks < 2; ++ks) {
                    const int dd = dt*16 + c;
                    const int e = (dd*KVBLK + 32*ks + 8*g) ^ vswz(dd);
                    bf16x8 bv = *(const bf16x8*)&ldsVT[e];
                    oacc[dt] = __builtin_amdgcn_mfma_f32_16x16x32_bf16(pa[ks], bv, oacc[dt], 0, 0, 0);
                }
            }
            __builtin_amdgcn_s_setprio(0);
        }
    }

    // ---- epilogue: O[q=qlo+4g+r][d=16dt+c] = oacc[dt][r] / l[q] ----
    const float linv = 1.0f / lrow;   // for q=qg
    f32x4 lq;
    #pragma unroll
    for (int r = 0; r < 4; ++r)
        lq[r] = __shfl(linv, 20*g + r, 64);
    #pragma unroll
    for (int r = 0; r < 4; ++r) {
        float* orow = O + (size_t)(qlo + 4*g + r)*STR + h*HD;
        #pragma unroll
        for (int dt = 0; dt < 8; ++dt)
            orow[dt*16 + c] = oacc[dt][r] * lq[r];
    }
    #undef LOAD_TILE
}

extern "C" void kernel_launch(void* const* d_in, const int* in_sizes, int n_in,
                              void* d_out, int out_size, void* d_ws, size_t ws_size,
                              hipStream_t stream) {
    const float* Q = (const float*)d_in[0];
    const float* K = (const float*)d_in[1];
    const float* V = (const float*)d_in[2];
    float* O = (float*)d_out;
    dim3 grid((SEQ / QBLK) * NH);   // 64 q-tiles x 16 heads = 1024 blocks
    dim3 block(256);
    fattn_kernel<<<grid, block, 0, stream>>>(Q, K, V, O);
}

// Round 8
// 166.806 us; speedup vs baseline: 6.7639x; 1.0244x over previous
//
#include <hip/hip_runtime.h>
#include <hip/hip_bf16.h>

typedef __bf16 bf16x8 __attribute__((ext_vector_type(8)));
typedef float  f32x4  __attribute__((ext_vector_type(4)));

#define SEQ  4096
#define NH   16
#define HD   128
#define QBLK 64
#define KVBLK 64
#define STR  (NH*HD)
#define THR  11.0f   // defer-max threshold (exp2 domain): p <= 2^11

__device__ __forceinline__ bf16x8 cvt_bf16x8(f32x4 a, f32x4 b, float scale) {
    bf16x8 v;
    v[0] = (__bf16)(a[0]*scale); v[1] = (__bf16)(a[1]*scale);
    v[2] = (__bf16)(a[2]*scale); v[3] = (__bf16)(a[3]*scale);
    v[4] = (__bf16)(b[0]*scale); v[5] = (__bf16)(b[1]*scale);
    v[6] = (__bf16)(b[2]*scale); v[7] = (__bf16)(b[3]*scale);
    return v;
}

// V^T swizzle: function of d only; keeps b128 reads/writes contiguous.
__device__ __forceinline__ int vswz(int d) { return ((d & 7) ^ ((d >> 3) & 7)) << 3; }

__global__ __launch_bounds__(256) void fattn_kernel(
    const float* __restrict__ Q, const float* __restrict__ K,
    const float* __restrict__ V, float* __restrict__ O)
{
    __shared__ __align__(16) __bf16 ldsK[KVBLK * HD];   // [key][d], 16 KB
    __shared__ __align__(16) __bf16 ldsVT[HD * KVBLK];  // [d][p] sigma-permuted, 16 KB

    const int tid  = threadIdx.x;
    const int lane = tid & 63;
    const int wv   = tid >> 6;
    const int c    = lane & 15;   // q index within 16 (swapped layout)
    const int g    = lane >> 4;   // 16-lane group 0..3

    // ---- balanced qb permutation: per-CU group {j,j+16,j+32,j+48} sums to 126 ----
    const int bid = blockIdx.x;
    const int h   = bid & (NH - 1);
    const int qt  = bid >> 4;
    const int jj  = qt & 15;
    int qb;
    switch (qt >> 4) {
        case 0:  qb = 63 - jj; break;   // heaviest first
        case 1:  qb = 32 + jj; break;
        case 2:  qb = 31 - jj; break;
        default: qb = jj;      break;
    }
    const int q0 = qb * QBLK;
    const int qg = q0 + wv*16 + c;

    // 1/sqrt(128) * log2(e): softmax runs in exp2 domain
    const float scale = 0.08838834764831845f * 1.4426950408889634f;

    // ---- Q fragment (B operand): lane holds Q[qg][32ks+8g .. +7] ----
    bf16x8 qf[4];
    {
        const float* qrow = Q + (size_t)qg * STR + h*HD;
        #pragma unroll
        for (int ks = 0; ks < 4; ++ks) {
            const int d0 = 32*ks + 8*g;
            f32x4 a = *(const f32x4*)(qrow + d0);
            f32x4 b = *(const f32x4*)(qrow + d0 + 4);
            qf[ks] = cvt_bf16x8(a, b, scale);
        }
    }

    f32x4 oacc[8];
    #pragma unroll
    for (int i = 0; i < 8; ++i) { oacc[i][0]=0.f; oacc[i][1]=0.f; oacc[i][2]=0.f; oacc[i][3]=0.f; }
    float mrow = -1e30f;   // running max (exp2 domain), lane-local for q=qg
    float lrow = 0.f;

    // ---- staging assignments ----
    bf16x8 kst[4];
    bf16x8 vt[4];                        // V^T: 4 d-cols x 8 sigma-consecutive p
    const int krb = tid >> 4;            // K row base
    const int kch = tid & 15;            // K 8-float chunk
    const int a_  = (lane >> 5) & 1;     // sigma block a
    const int gp  = (lane >> 3) & 3;     // sigma g'
    const int cg  = 8*wv + (lane & 7);   // d col-group 0..31
    const int vr0 = 32*a_ + 4*gp;        // kv row base (u<4); +16 for u>=4
    const int pb  = 32*a_ + 8*gp;        // sigma p base (8 consecutive slots)
    const int vd_ = 4*cg;                // d cols base

    #define LOAD_TILE(K0)                                                        \
    {                                                                            \
        _Pragma("unroll")                                                        \
        for (int it = 0; it < 4; ++it) {                                         \
            const int row = it*16 + krb;                                         \
            const float* src = K + (size_t)((K0)+row)*STR + h*HD + kch*8;        \
            f32x4 a = *(const f32x4*)src;                                        \
            f32x4 b = *(const f32x4*)(src + 4);                                  \
            kst[it] = cvt_bf16x8(a, b, 1.0f);                                    \
        }                                                                        \
        _Pragma("unroll")                                                        \
        for (int u = 0; u < 8; ++u) {                                            \
            const int kr = (K0) + vr0 + 16*(u>>2) + (u&3);                       \
            f32x4 va = *(const f32x4*)(V + (size_t)kr*STR + h*HD + vd_);         \
            vt[0][u] = (__bf16)va[0]; vt[1][u] = (__bf16)va[1];                  \
            vt[2][u] = (__bf16)va[2]; vt[3][u] = (__bf16)va[3];                  \
        }                                                                        \
    }

    const int nkv = qb + 1;
    LOAD_TILE(0);

    const int qlo = q0 + wv*16;

    for (int kb = 0; kb < nkv; ++kb) {
        const int k0 = kb * KVBLK;

        __syncthreads();   // previous iteration's LDS reads complete
        // ---- reg -> LDS: K tile [key][d], b128 swizzled ----
        #pragma unroll
        for (int it = 0; it < 4; ++it) {
            const int row = it*16 + krb;
            const int e = (row*HD + kch*8) ^ ((row & 7) << 3);
            *(bf16x8*)&ldsK[e] = kst[it];
        }
        // ---- reg -> LDS: V^T tile, b128 at sigma base (full bank coverage) ----
        #pragma unroll
        for (int i = 0; i < 4; ++i) {
            const int d = vd_ + i;
            const int e = (d*KVBLK + pb) ^ vswz(d);
            *(bf16x8*)&ldsVT[e] = vt[i];
        }
        __syncthreads();

        // ---- issue next tile's global loads (latency hides under compute) ----
        if (kb + 1 < nkv) LOAD_TILE(k0 + KVBLK);

        if (k0 <= qlo + 15) {   // else: fully masked for this wave's q rows
            // ---- swapped QK^T: lane gets S^T[k0+16t+4g+r][qg] ----
            f32x4 s[4];
            __builtin_amdgcn_s_setprio(1);
            #pragma unroll
            for (int t = 0; t < 4; ++t) {
                f32x4 acc = {0.f,0.f,0.f,0.f};
                #pragma unroll
                for (int ks = 0; ks < 4; ++ks) {
                    const int row = t*16 + c;
                    const int e = (row*HD + 32*ks + 8*g) ^ ((row & 7) << 3);
                    bf16x8 ak = *(const bf16x8*)&ldsK[e];
                    acc = __builtin_amdgcn_mfma_f32_16x16x32_bf16(ak, qf[ks], acc, 0, 0, 0);
                }
                s[t] = acc;
            }
            __builtin_amdgcn_s_setprio(0);

            // ---- causal mask: diagonal tile only ----
            if (kb == qb) {
                #pragma unroll
                for (int t = 0; t < 4; ++t)
                    #pragma unroll
                    for (int r = 0; r < 4; ++r)
                        if (k0 + 16*t + 4*g + r > qg) s[t][r] = -1e30f;
            }

            // ---- online softmax (exp2 domain, defer-max) ----
            float pmax = fmaxf(
                fmaxf(fmaxf(fmaxf(s[0][0],s[0][1]),fmaxf(s[0][2],s[0][3])),
                      fmaxf(fmaxf(s[1][0],s[1][1]),fmaxf(s[1][2],s[1][3]))),
                fmaxf(fmaxf(fmaxf(s[2][0],s[2][1]),fmaxf(s[2][2],s[2][3])),
                      fmaxf(fmaxf(s[3][0],s[3][1]),fmaxf(s[3][2],s[3][3]))));
            pmax = fmaxf(pmax, __shfl_xor(pmax, 16, 64));
            pmax = fmaxf(pmax, __shfl_xor(pmax, 32, 64));
            if (!__all(pmax - mrow <= THR)) {
                const float mn = fmaxf(mrow, pmax);
                const float alpha = exp2f(mrow - mn);
                mrow = mn;
                f32x4 aq;
                #pragma unroll
                for (int r = 0; r < 4; ++r)
                    aq[r] = __shfl(alpha, 20*g + r, 64);   // lane 16g + (4g+r)
                #pragma unroll
                for (int dt = 0; dt < 8; ++dt)
                    oacc[dt] *= aq;
                lrow *= alpha;
            }
            float rs = 0.f;
            #pragma unroll
            for (int t = 0; t < 4; ++t)
                #pragma unroll
                for (int r = 0; r < 4; ++r) {
                    const float p = exp2f(s[t][r] - mrow);
                    s[t][r] = p;
                    rs += p;
                }
            rs += __shfl_xor(rs, 16, 64);
            rs += __shfl_xor(rs, 32, 64);
            lrow += rs;

            // ---- P -> A-fragment: pure register repack ----
            bf16x8 pa[2];
            #pragma unroll
            for (int ks = 0; ks < 2; ++ks) {
                bf16x8 v;
                v[0]=(__bf16)s[2*ks][0];   v[1]=(__bf16)s[2*ks][1];
                v[2]=(__bf16)s[2*ks][2];   v[3]=(__bf16)s[2*ks][3];
                v[4]=(__bf16)s[2*ks+1][0]; v[5]=(__bf16)s[2*ks+1][1];
                v[6]=(__bf16)s[2*ks+1][2]; v[7]=(__bf16)s[2*ks+1][3];
                pa[ks] = v;
            }

            // ---- PV ----
            __builtin_amdgcn_s_setprio(1);
            #pragma unroll
            for (int dt = 0; dt < 8; ++dt) {
                #pragma unroll
                for (int ks = 0; ks < 2; ++ks) {
                    const int dd = dt*16 + c;
                    const int e = (dd*KVBLK + 32*ks + 8*g) ^ vswz(dd);
                    bf16x8 bv = *(const bf16x8*)&ldsVT[e];
                    oacc[dt] = __builtin_amdgcn_mfma_f32_16x16x32_bf16(pa[ks], bv, oacc[dt], 0, 0, 0);
                }
            }
            __builtin_amdgcn_s_setprio(0);
        }
    }

    // ---- epilogue: O[q=qlo+4g+r][d=16dt+c] = oacc[dt][r] / l[q] ----
    const float linv = 1.0f / lrow;
    f32x4 lq;
    #pragma unroll
    for (int r = 0; r < 4; ++r)
        lq[r] = __shfl(linv, 20*g + r, 64);
    #pragma unroll
    for (int r = 0; r < 4; ++r) {
        float* orow = O + (size_t)(qlo + 4*g + r)*STR + h*HD;
        #pragma unroll
        for (int dt = 0; dt < 8; ++dt)
            orow[dt*16 + c] = oacc[dt][r] * lq[r];
    }
    #undef LOAD_TILE
}

extern "C" void kernel_launch(void* const* d_in, const int* in_sizes, int n_in,
                              void* d_out, int out_size, void* d_ws, size_t ws_size,
                              hipStream_t stream) {
    const float* Q = (const float*)d_in[0];
    const float* K = (const float*)d_in[1];
    const float* V = (const float*)d_in[2];
    float* O = (float*)d_out;
    dim3 grid((SEQ / QBLK) * NH);   // 64 q-tiles x 16 heads = 1024 blocks
    dim3 block(256);
    fattn_kernel<<<grid, block, 0, stream>>>(Q, K, V, O);
}

// Round 9
// 152.087 us; speedup vs baseline: 7.4185x; 1.0968x over previous
//
#include <hip/hip_runtime.h>
#include <hip/hip_bf16.h>

typedef __bf16 bf16x8 __attribute__((ext_vector_type(8)));
typedef float  f32x4  __attribute__((ext_vector_type(4)));

#define SEQ  4096
#define NH   16
#define HD   128
#define KVBLK 64
#define NT   (SEQ / KVBLK)     // 64 kv tiles
#define STR  (NH * HD)         // 2048 floats per seq position
#define TILE_E 8192            // elems per bf16 tile image (64*128)
#define WS_ELEMS ((size_t)NH * NT * TILE_E)   // per K or V
#define THR  11.0f             // defer-max threshold (exp2 domain)

__device__ __forceinline__ bf16x8 cvt_bf16x8(f32x4 a, f32x4 b, float scale) {
    bf16x8 v;
    v[0] = (__bf16)(a[0]*scale); v[1] = (__bf16)(a[1]*scale);
    v[2] = (__bf16)(a[2]*scale); v[3] = (__bf16)(a[3]*scale);
    v[4] = (__bf16)(b[0]*scale); v[5] = (__bf16)(b[1]*scale);
    v[6] = (__bf16)(b[2]*scale); v[7] = (__bf16)(b[3]*scale);
    return v;
}

__device__ __forceinline__ int vswz(int d) { return ((d & 7) ^ ((d >> 3) & 7)) << 3; }

// ================= prep: build bf16 swizzled tile images in ws =================
__global__ __launch_bounds__(256) void prep_kernel(
    const float* __restrict__ K, const float* __restrict__ V, __bf16* __restrict__ ws)
{
    const int tid  = threadIdx.x;
    const int lane = tid & 63;
    const int wv   = tid >> 6;
    const int bid  = blockIdx.x;
    const int h    = bid >> 6;
    const int t    = bid & 63;

    __bf16* kimg = ws + (size_t)(h*NT + t) * TILE_E;
    __bf16* vimg = ws + WS_ELEMS + (size_t)(h*NT + t) * TILE_E;

    // K image: [row][d] with e = (row*128 + ch*8) ^ ((row&7)<<3)
    const int krb = tid >> 4, kch = tid & 15;
    #pragma unroll
    for (int it = 0; it < 4; ++it) {
        const int row = it*16 + krb;
        const float* src = K + (size_t)(t*KVBLK + row)*STR + h*HD + kch*8;
        f32x4 a = *(const f32x4*)src;
        f32x4 b = *(const f32x4*)(src + 4);
        const int e = (row*HD + kch*8) ^ ((row & 7) << 3);
        *(bf16x8*)&kimg[e] = cvt_bf16x8(a, b, 1.0f);
    }

    // V image: [d][p] sigma-permuted, e = (d*64 + p) ^ vswz(d)
    const int a_ = (lane >> 5) & 1;
    const int gp = (lane >> 3) & 3;
    const int cg = 8*wv + (lane & 7);
    const int vr0 = 32*a_ + 4*gp;
    const int pb  = 32*a_ + 8*gp;
    const int vd_ = 4*cg;
    bf16x8 vt[4];
    #pragma unroll
    for (int u = 0; u < 8; ++u) {
        const int kr = t*KVBLK + vr0 + 16*(u>>2) + (u&3);
        f32x4 va = *(const f32x4*)(V + (size_t)kr*STR + h*HD + vd_);
        vt[0][u] = (__bf16)va[0]; vt[1][u] = (__bf16)va[1];
        vt[2][u] = (__bf16)va[2]; vt[3][u] = (__bf16)va[3];
    }
    #pragma unroll
    for (int i = 0; i < 4; ++i) {
        const int d = vd_ + i;
        const int e = (d*KVBLK + pb) ^ vswz(d);
        *(bf16x8*)&vimg[e] = vt[i];
    }
}

// ================= main: paired q-tiles, gload_lds dbuf =================
__global__ __launch_bounds__(256) void fattn2_kernel(
    const float* __restrict__ Q, const __bf16* __restrict__ ws, float* __restrict__ O)
{
    __shared__ __align__(16) __bf16 lds[2][2][TILE_E];   // [buf][K=0/V=1][e], 64 KB

    const int tid  = threadIdx.x;
    const int lane = tid & 63;
    const int wv   = tid >> 6;
    const int c    = lane & 15;
    const int g    = lane >> 4;

    const int bid = blockIdx.x;
    const int h   = bid & (NH - 1);
    const int j   = bid >> 4;            // pair index 0..31
    const int qbH = 63 - j, qbL = j;
    const int nkvH = qbH + 1;
    const int nt   = nkvH + qbL + 1;     // = 65, uniform across blocks

    const float scale = 0.08838834764831845f * 1.4426950408889634f; // /sqrt(128)*log2e

    // ---- Q fragments for both phases ----
    bf16x8 qfH[4], qfL[4];
    {
        const float* qrH = Q + (size_t)(qbH*KVBLK + wv*16 + c) * STR + h*HD;
        const float* qrL = Q + (size_t)(qbL*KVBLK + wv*16 + c) * STR + h*HD;
        #pragma unroll
        for (int ks = 0; ks < 4; ++ks) {
            const int d0 = 32*ks + 8*g;
            qfH[ks] = cvt_bf16x8(*(const f32x4*)(qrH + d0), *(const f32x4*)(qrH + d0 + 4), scale);
            qfL[ks] = cvt_bf16x8(*(const f32x4*)(qrL + d0), *(const f32x4*)(qrL + d0 + 4), scale);
        }
    }
    bf16x8 qcur[4];
    #pragma unroll
    for (int ks = 0; ks < 4; ++ks) qcur[ks] = qfH[ks];

    int curqb = qbH;
    int qg    = qbH*KVBLK + wv*16 + c;
    int qlo   = qbH*KVBLK + wv*16;

    f32x4 oacc[8];
    #pragma unroll
    for (int i = 0; i < 8; ++i) { oacc[i][0]=0.f; oacc[i][1]=0.f; oacc[i][2]=0.f; oacc[i][3]=0.f; }
    float mrow = -1e30f, lrow = 0.f;

    const __bf16* kws = ws;
    const __bf16* vws = ws + WS_ELEMS;
    char* ldsbase = (char*)&lds[0][0][0];

    // issue one tile's 16KB K-image + 16KB V-image: wave wv takes chunks [4wv..4wv+3]
    #define ISSUE(TT, BUF)                                                          \
    {                                                                               \
        const size_t tb = (size_t)(h*NT + (TT)) * TILE_E;                           \
        _Pragma("unroll")                                                           \
        for (int ci = 0; ci < 4; ++ci) {                                            \
            const int ch = wv*4 + ci;                                               \
            const __bf16* gk = kws + tb + ch*512 + lane*8;                          \
            const __bf16* gv = vws + tb + ch*512 + lane*8;                          \
            __builtin_amdgcn_global_load_lds(                                       \
                (const __attribute__((address_space(1))) void*)gk,                  \
                (__attribute__((address_space(3))) void*)(ldsbase + (BUF)*32768 + ch*1024),          \
                16, 0, 0);                                                          \
            __builtin_amdgcn_global_load_lds(                                       \
                (const __attribute__((address_space(1))) void*)gv,                  \
                (__attribute__((address_space(3))) void*)(ldsbase + (BUF)*32768 + 16384 + ch*1024),  \
                16, 0, 0);                                                          \
        }                                                                           \
    }

    #define EPILOGUE()                                                              \
    {                                                                               \
        const float linv = 1.0f / lrow;                                             \
        f32x4 lq;                                                                   \
        _Pragma("unroll")                                                           \
        for (int r = 0; r < 4; ++r) lq[r] = __shfl(linv, 20*g + r, 64);             \
        _Pragma("unroll")                                                           \
        for (int r = 0; r < 4; ++r) {                                               \
            float* orow = O + (size_t)(qlo + 4*g + r)*STR + h*HD;                   \
            _Pragma("unroll")                                                       \
            for (int dt = 0; dt < 8; ++dt)                                          \
                orow[dt*16 + c] = oacc[dt][r] * lq[r];                              \
        }                                                                           \
    }

    ISSUE(0, 0);
    int buf = 0;

    for (int t = 0; t < nt; ++t) {
        // ---- phase switch: finish heavy q-tile, start light one ----
        if (t == nkvH) {
            EPILOGUE();
            #pragma unroll
            for (int i = 0; i < 8; ++i) { oacc[i][0]=0.f; oacc[i][1]=0.f; oacc[i][2]=0.f; oacc[i][3]=0.f; }
            mrow = -1e30f; lrow = 0.f;
            #pragma unroll
            for (int ks = 0; ks < 4; ++ks) qcur[ks] = qfL[ks];
            curqb = qbL;
            qg  = qbL*KVBLK + wv*16 + c;
            qlo = qbL*KVBLK + wv*16;
        }
        const int tt = (t < nkvH) ? t : t - nkvH;

        __syncthreads();   // drains vmcnt -> tile t's image resident; joins waves
        if (t + 1 < nt) {
            const int tn = (t + 1 < nkvH) ? t + 1 : t + 1 - nkvH;
            ISSUE(tn, buf ^ 1);
        }

        const __bf16* bK = &lds[buf][0][0];
        const __bf16* bV = &lds[buf][1][0];

        // ---- swapped QK^T: lane gets S^T[k=16t'+4g+r][qg] ----
        f32x4 s[4];
        __builtin_amdgcn_s_setprio(1);
        #pragma unroll
        for (int tq = 0; tq < 4; ++tq) {
            f32x4 acc = {0.f,0.f,0.f,0.f};
            #pragma unroll
            for (int ks = 0; ks < 4; ++ks) {
                const int row = tq*16 + c;
                const int e = (row*HD + 32*ks + 8*g) ^ ((row & 7) << 3);
                bf16x8 ak = *(const bf16x8*)&bK[e];
                acc = __builtin_amdgcn_mfma_f32_16x16x32_bf16(ak, qcur[ks], acc, 0, 0, 0);
            }
            s[tq] = acc;
        }
        __builtin_amdgcn_s_setprio(0);

        // ---- causal mask: diagonal tile only ----
        if (tt == curqb) {
            const int k0 = tt * KVBLK;
            #pragma unroll
            for (int tq = 0; tq < 4; ++tq)
                #pragma unroll
                for (int r = 0; r < 4; ++r)
                    if (k0 + 16*tq + 4*g + r > qg) s[tq][r] = -1e30f;
        }

        // ---- online softmax (exp2 domain, defer-max) ----
        float pmax = fmaxf(
            fmaxf(fmaxf(fmaxf(s[0][0],s[0][1]),fmaxf(s[0][2],s[0][3])),
                  fmaxf(fmaxf(s[1][0],s[1][1]),fmaxf(s[1][2],s[1][3]))),
            fmaxf(fmaxf(fmaxf(s[2][0],s[2][1]),fmaxf(s[2][2],s[2][3])),
                  fmaxf(fmaxf(s[3][0],s[3][1]),fmaxf(s[3][2],s[3][3]))));
        pmax = fmaxf(pmax, __shfl_xor(pmax, 16, 64));
        pmax = fmaxf(pmax, __shfl_xor(pmax, 32, 64));
        if (!__all(pmax - mrow <= THR)) {
            const float mn = fmaxf(mrow, pmax);
            const float alpha = exp2f(mrow - mn);
            mrow = mn;
            f32x4 aq;
            #pragma unroll
            for (int r = 0; r < 4; ++r) aq[r] = __shfl(alpha, 20*g + r, 64);
            #pragma unroll
            for (int dt = 0; dt < 8; ++dt) oacc[dt] *= aq;
            lrow *= alpha;
        }
        float rs = 0.f;
        #pragma unroll
        for (int tq = 0; tq < 4; ++tq)
            #pragma unroll
            for (int r = 0; r < 4; ++r) {
                const float p = exp2f(s[tq][r] - mrow);
                s[tq][r] = p;
                rs += p;
            }
        rs += __shfl_xor(rs, 16, 64);
        rs += __shfl_xor(rs, 32, 64);
        lrow += rs;

        // ---- P -> A-fragment: pure register repack ----
        bf16x8 pa[2];
        #pragma unroll
        for (int ks = 0; ks < 2; ++ks) {
            bf16x8 v;
            v[0]=(__bf16)s[2*ks][0];   v[1]=(__bf16)s[2*ks][1];
            v[2]=(__bf16)s[2*ks][2];   v[3]=(__bf16)s[2*ks][3];
            v[4]=(__bf16)s[2*ks+1][0]; v[5]=(__bf16)s[2*ks+1][1];
            v[6]=(__bf16)s[2*ks+1][2]; v[7]=(__bf16)s[2*ks+1][3];
            pa[ks] = v;
        }

        // ---- PV ----
        __builtin_amdgcn_s_setprio(1);
        #pragma unroll
        for (int dt = 0; dt < 8; ++dt) {
            #pragma unroll
            for (int ks = 0; ks < 2; ++ks) {
                const int dd = dt*16 + c;
                const int e = (dd*KVBLK + 32*ks + 8*g) ^ vswz(dd);
                bf16x8 bv = *(const bf16x8*)&bV[e];
                oacc[dt] = __builtin_amdgcn_mfma_f32_16x16x32_bf16(pa[ks], bv, oacc[dt], 0, 0, 0);
            }
        }
        __builtin_amdgcn_s_setprio(0);

        buf ^= 1;
    }

    EPILOGUE();
    #undef ISSUE
    #undef EPILOGUE
}

// ================= fallback (R8 kernel) if ws too small =================
__global__ __launch_bounds__(256) void fattn_fallback(
    const float* __restrict__ Q, const float* __restrict__ K,
    const float* __restrict__ V, float* __restrict__ O)
{
    __shared__ __align__(16) __bf16 ldsK[KVBLK * HD];
    __shared__ __align__(16) __bf16 ldsVT[HD * KVBLK];

    const int tid  = threadIdx.x;
    const int lane = tid & 63;
    const int wv   = tid >> 6;
    const int c    = lane & 15;
    const int g    = lane >> 4;

    const int bid = blockIdx.x;
    const int h   = bid & (NH - 1);
    const int qt  = bid >> 4;
    const int jj  = qt & 15;
    int qb;
    switch (qt >> 4) {
        case 0:  qb = 63 - jj; break;
        case 1:  qb = 32 + jj; break;
        case 2:  qb = 31 - jj; break;
        default: qb = jj;      break;
    }
    const int q0 = qb * KVBLK;
    const int qg = q0 + wv*16 + c;

    const float scale = 0.08838834764831845f * 1.4426950408889634f;

    bf16x8 qf[4];
    {
        const float* qrow = Q + (size_t)qg * STR + h*HD;
        #pragma unroll
        for (int ks = 0; ks < 4; ++ks) {
            const int d0 = 32*ks + 8*g;
            qf[ks] = cvt_bf16x8(*(const f32x4*)(qrow + d0), *(const f32x4*)(qrow + d0 + 4), scale);
        }
    }

    f32x4 oacc[8];
    #pragma unroll
    for (int i = 0; i < 8; ++i) { oacc[i][0]=0.f; oacc[i][1]=0.f; oacc[i][2]=0.f; oacc[i][3]=0.f; }
    float mrow = -1e30f, lrow = 0.f;

    bf16x8 kst[4];
    bf16x8 vt[4];
    const int krb = tid >> 4, kch = tid & 15;
    const int a_  = (lane >> 5) & 1;
    const int gp  = (lane >> 3) & 3;
    const int cg  = 8*wv + (lane & 7);
    const int vr0 = 32*a_ + 4*gp;
    const int pb  = 32*a_ + 8*gp;
    const int vd_ = 4*cg;

    #define LOAD_TILE(K0)                                                        \
    {                                                                            \
        _Pragma("unroll")                                                        \
        for (int it = 0; it < 4; ++it) {                                         \
            const int row = it*16 + krb;                                         \
            const float* src = K + (size_t)((K0)+row)*STR + h*HD + kch*8;        \
            kst[it] = cvt_bf16x8(*(const f32x4*)src, *(const f32x4*)(src+4), 1.0f); \
        }                                                                        \
        _Pragma("unroll")                                                        \
        for (int u = 0; u < 8; ++u) {                                            \
            const int kr = (K0) + vr0 + 16*(u>>2) + (u&3);                       \
            f32x4 va = *(const f32x4*)(V + (size_t)kr*STR + h*HD + vd_);         \
            vt[0][u] = (__bf16)va[0]; vt[1][u] = (__bf16)va[1];                  \
            vt[2][u] = (__bf16)va[2]; vt[3][u] = (__bf16)va[3];                  \
        }                                                                        \
    }

    const int nkv = qb + 1;
    LOAD_TILE(0);
    const int qlo = q0 + wv*16;

    for (int kb = 0; kb < nkv; ++kb) {
        const int k0 = kb * KVBLK;
        __syncthreads();
        #pragma unroll
        for (int it = 0; it < 4; ++it) {
            const int row = it*16 + krb;
            const int e = (row*HD + kch*8) ^ ((row & 7) << 3);
            *(bf16x8*)&ldsK[e] = kst[it];
        }
        #pragma unroll
        for (int i = 0; i < 4; ++i) {
            const int d = vd_ + i;
            const int e = (d*KVBLK + pb) ^ vswz(d);
            *(bf16x8*)&ldsVT[e] = vt[i];
        }
        __syncthreads();
        if (kb + 1 < nkv) LOAD_TILE(k0 + KVBLK);

        f32x4 s[4];
        __builtin_amdgcn_s_setprio(1);
        #pragma unroll
        for (int t = 0; t < 4; ++t) {
            f32x4 acc = {0.f,0.f,0.f,0.f};
            #pragma unroll
            for (int ks = 0; ks < 4; ++ks) {
                const int row = t*16 + c;
                const int e = (row*HD + 32*ks + 8*g) ^ ((row & 7) << 3);
                acc = __builtin_amdgcn_mfma_f32_16x16x32_bf16(*(const bf16x8*)&ldsK[e], qf[ks], acc, 0, 0, 0);
            }
            s[t] = acc;
        }
        __builtin_amdgcn_s_setprio(0);

        if (kb == qb) {
            #pragma unroll
            for (int t = 0; t < 4; ++t)
                #pragma unroll
                for (int r = 0; r < 4; ++r)
                    if (k0 + 16*t + 4*g + r > qg) s[t][r] = -1e30f;
        }

        float pmax = fmaxf(
            fmaxf(fmaxf(fmaxf(s[0][0],s[0][1]),fmaxf(s[0][2],s[0][3])),
                  fmaxf(fmaxf(s[1][0],s[1][1]),fmaxf(s[1][2],s[1][3]))),
            fmaxf(fmaxf(fmaxf(s[2][0],s[2][1]),fmaxf(s[2][2],s[2][3])),
                  fmaxf(fmaxf(s[3][0],s[3][1]),fmaxf(s[3][2],s[3][3]))));
        pmax = fmaxf(pmax, __shfl_xor(pmax, 16, 64));
        pmax = fmaxf(pmax, __shfl_xor(pmax, 32, 64));
        if (!__all(pmax - mrow <= THR)) {
            const float mn = fmaxf(mrow, pmax);
            const float alpha = exp2f(mrow - mn);
            mrow = mn;
            f32x4 aq;
            #pragma unroll
            for (int r = 0; r < 4; ++r) aq[r] = __shfl(alpha, 20*g + r, 64);
            #pragma unroll
            for (int dt = 0; dt < 8; ++dt) oacc[dt] *= aq;
            lrow *= alpha;
        }
        float rs = 0.f;
        #pragma unroll
        for (int t = 0; t < 4; ++t)
            #pragma unroll
            for (int r = 0; r < 4; ++r) {
                const float p = exp2f(s[t][r] - mrow);
                s[t][r] = p;
                rs += p;
            }
        rs += __shfl_xor(rs, 16, 64);
        rs += __shfl_xor(rs, 32, 64);
        lrow += rs;

        bf16x8 pa[2];
        #pragma unroll
        for (int ks = 0; ks < 2; ++ks) {
            bf16x8 v;
            v[0]=(__bf16)s[2*ks][0];   v[1]=(__bf16)s[2*ks][1];
            v[2]=(__bf16)s[2*ks][2];   v[3]=(__bf16)s[2*ks][3];
            v[4]=(__bf16)s[2*ks+1][0]; v[5]=(__bf16)s[2*ks+1][1];
            v[6]=(__bf16)s[2*ks+1][2]; v[7]=(__bf16)s[2*ks+1][3];
            pa[ks] = v;
        }

        __builtin_amdgcn_s_setprio(1);
        #pragma unroll
        for (int dt = 0; dt < 8; ++dt) {
            #pragma unroll
            for (int ks = 0; ks < 2; ++ks) {
                const int dd = dt*16 + c;
                const int e = (dd*KVBLK + 32*ks + 8*g) ^ vswz(dd);
                oacc[dt] = __builtin_amdgcn_mfma_f32_16x16x32_bf16(pa[ks], *(const bf16x8*)&ldsVT[e], oacc[dt], 0, 0, 0);
            }
        }
        __builtin_amdgcn_s_setprio(0);
    }

    const float linv = 1.0f / lrow;
    f32x4 lq;
    #pragma unroll
    for (int r = 0; r < 4; ++r) lq[r] = __shfl(linv, 20*g + r, 64);
    #pragma unroll
    for (int r = 0; r < 4; ++r) {
        float* orow = O + (size_t)(qlo + 4*g + r)*STR + h*HD;
        #pragma unroll
        for (int dt = 0; dt < 8; ++dt)
            orow[dt*16 + c] = oacc[dt][r] * lq[r];
    }
    #undef LOAD_TILE
}

extern "C" void kernel_launch(void* const* d_in, const int* in_sizes, int n_in,
                              void* d_out, int out_size, void* d_ws, size_t ws_size,
                              hipStream_t stream) {
    const float* Q = (const float*)d_in[0];
    const float* K = (const float*)d_in[1];
    const float* V = (const float*)d_in[2];
    float* O = (float*)d_out;

    const size_t need = 2 * WS_ELEMS * sizeof(__bf16);   // 32 MB
    if (ws_size >= need) {
        prep_kernel<<<dim3(NH * NT), dim3(256), 0, stream>>>(K, V, (__bf16*)d_ws);
        fattn2_kernel<<<dim3(NH * 32), dim3(256), 0, stream>>>(Q, (const __bf16*)d_ws, O);
    } else {
        fattn_fallback<<<dim3((SEQ/KVBLK) * NH), dim3(256), 0, stream>>>(Q, K, V, O);
    }
}